// Round 4
// baseline (4493.229 us; speedup 1.0000x reference)
//
#include <hip/hip_runtime.h>
#include <math.h>

#define B 8
#define P 2048
#define D 64
#define EPS 0.1f
#define INVEPS 10.0f
#define MAXIT 100
#define THRESH 0.1f
#define ROWS_PER_BLK 32            // 8 waves x 4 rows
#define NBLK_A (B * P / ROWS_PER_BLK)   // 512 blocks
#define PLANES (P / ROWS_PER_BLK)       // 64 partial planes per batch

#define S2F   14.4269504089f       // 10 * log2(e)   (scale into exp2 domain)
#define NS2F (-14.4269504089f)
#define EPSLN2 0.069314718056f     // EPS * ln(2)

// exp2/log2: avoid __exp2f/__log2f spellings (collide with glibc math.h
// internal decls). Use AMDGCN builtins (v_exp_f32 / v_log_f32) on device.
#if defined(__AMDGCN__) && __has_builtin(__builtin_amdgcn_exp2f)
#define EXP2F(x) __builtin_amdgcn_exp2f(x)
#else
#define EXP2F(x) exp2f(x)
#endif
#if defined(__AMDGCN__) && __has_builtin(__builtin_amdgcn_logf)
#define LOG2F(x) __builtin_amdgcn_logf(x)
#else
#define LOG2F(x) log2f(x)
#endif

// ---------------- C build: C[b,i,j] = sum_d (x[b,i,d]-y[b,j,d])^2 ----------
__global__ __launch_bounds__(256) void build_C(const float* __restrict__ x,
                                               const float* __restrict__ y,
                                               float* __restrict__ C) {
    __shared__ float xs[64 * 68];
    __shared__ float ys[64 * 68];
    const int tid = threadIdx.x;
    const int blk = blockIdx.x;        // 8 * 32 * 32 = 8192 blocks
    const int b   = blk >> 10;
    const int rem = blk & 1023;
    const int i0  = (rem >> 5) << 6;
    const int j0  = (rem & 31) << 6;

    const float4* xg = (const float4*)(x + ((size_t)(b * P + i0)) * D);
    const float4* yg = (const float4*)(y + ((size_t)(b * P + j0)) * D);
#pragma unroll
    for (int p = 0; p < 4; ++p) {
        int q = tid + (p << 8);
        int row = q >> 4, c4 = q & 15;
        float4 xv = xg[row * 16 + c4];
        float4 yv = yg[row * 16 + c4];
        float* xd = &xs[row * 68 + (c4 << 2)];
        xd[0] = xv.x; xd[1] = xv.y; xd[2] = xv.z; xd[3] = xv.w;
        float* yd = &ys[row * 68 + (c4 << 2)];
        yd[0] = yv.x; yd[1] = yv.y; yd[2] = yv.z; yd[3] = yv.w;
    }
    __syncthreads();

    const int ti = tid >> 4, tj = tid & 15;
    float acc[4][4] = {};
#pragma unroll 4
    for (int d4 = 0; d4 < 16; ++d4) {
        float4 xa[4], yb[4];
#pragma unroll
        for (int a = 0; a < 4; ++a)
            xa[a] = *(const float4*)&xs[(ti * 4 + a) * 68 + (d4 << 2)];
#pragma unroll
        for (int bb = 0; bb < 4; ++bb)
            yb[bb] = *(const float4*)&ys[(tj * 4 + bb) * 68 + (d4 << 2)];
#pragma unroll
        for (int a = 0; a < 4; ++a)
#pragma unroll
            for (int bb = 0; bb < 4; ++bb) {
                float dx = xa[a].x - yb[bb].x;
                float dy = xa[a].y - yb[bb].y;
                float dz = xa[a].z - yb[bb].z;
                float dw = xa[a].w - yb[bb].w;
                acc[a][bb] += dx * dx + dy * dy + dz * dz + dw * dw;
            }
    }
    size_t base = ((size_t)b * P + (i0 + ti * 4)) * P + (j0 + tj * 4);
#pragma unroll
    for (int a = 0; a < 4; ++a) {
        float4 o = make_float4(acc[a][0], acc[a][1], acc[a][2], acc[a][3]);
        *(float4*)&C[base + (size_t)a * P] = o;
    }
}

// -------- online logsumexp helpers (exp2 domain: state m=max(z2), s=sum 2^(z2-m)) ----
__device__ __forceinline__ void lse_push2(float z, float& m, float& s) {
    float d = z - m;
    float w = EXP2F(-fabsf(d));       // 2^(min-max); first push: d=+inf -> w=0
    bool gt = d > 0.0f;
    m = gt ? z : m;
    s = fmaf(s, gt ? w : 1.0f, gt ? 1.0f : w);
}
__device__ __forceinline__ void lse_merge2(float mo, float so, float& m, float& s) {
    float M = fmaxf(m, mo);
    s = s * EXP2F(m - M) + so * EXP2F(mo - M);
    m = M;
}

// ---------------- init: zero u, v, err accumulators, done flags, cost ------
__global__ void init_ws(float* __restrict__ u, float* __restrict__ v,
                        float* __restrict__ errAcc, unsigned* __restrict__ doneArr,
                        float* __restrict__ cost) {
    int idx = blockIdx.x * blockDim.x + threadIdx.x;
    if (idx < B * P) { u[idx] = 0.0f; v[idx] = 0.0f; }
    if (idx < MAXIT) errAcc[idx] = 0.0f;
    if (idx <= MAXIT) doneArr[idx] = 0u;
    if (idx < B) cost[idx] = 0.0f;
}

// ---- iteration kernel A: barrier-free C sweep -----------------------------
// 512 threads = 8 waves; wave owns 4 whole rows. Per row: load 8 float4 into
// registers, row-LSE from registers (butterfly reduce), then push the SAME
// registers into per-lane column chains (32 cols/lane, 64 VGPRs). Next-row
// loads are issued into each freed pf[k] slot inside the col-push loop, so
// global loads stay in flight continuously — no LDS staging, no per-slab
// barriers. Cross-wave column merge once at the end via 3-round LDS tree.
template <bool MORE>
__device__ __forceinline__ void row_body(
        const float* __restrict__ Cb, const float* __restrict__ sv,
        float* __restrict__ u, int b, int r, int lane,
        float4 (&pf)[8], float (&cm)[8][4], float (&cs)[8][4],
        float& werr, float eps_logmu) {
    // ---- row LSE (registers + sv in LDS) ----
    float rm[4] = {-INFINITY, -INFINITY, -INFINITY, -INFINITY};
    float rs[4] = {0.0f, 0.0f, 0.0f, 0.0f};
#pragma unroll
    for (int k = 0; k < 8; ++k) {
        float4 c4 = pf[k];
        float4 v4 = ((const float4*)sv)[lane + (k << 6)];
        lse_push2(fmaf(c4.x, NS2F, v4.x), rm[0], rs[0]);
        lse_push2(fmaf(c4.y, NS2F, v4.y), rm[1], rs[1]);
        lse_push2(fmaf(c4.z, NS2F, v4.z), rm[2], rs[2]);
        lse_push2(fmaf(c4.w, NS2F, v4.w), rm[3], rs[3]);
    }
    lse_merge2(rm[1], rs[1], rm[0], rs[0]);
    lse_merge2(rm[3], rs[3], rm[2], rs[2]);
    lse_merge2(rm[2], rs[2], rm[0], rs[0]);
#pragma unroll
    for (int off = 32; off; off >>= 1) {
        float mo = __shfl_xor(rm[0], off, 64);
        float so = __shfl_xor(rs[0], off, 64);
        lse_merge2(mo, so, rm[0], rs[0]);
    }
    // LSE_e = ln2 * (m2 + log2(s))
    float unew = eps_logmu - EPSLN2 * (rm[0] + LOG2F(rs[0]));
    if (lane == 0) {
        int gi = b * P + r;
        werr += fabsf(unew - u[gi]);
        u[gi] = unew;
    }
    float u2 = unew * S2F;
    // ---- col pushes; reload freed pf slots with next row ----
    const float4* CrowN = (const float4*)(Cb + (size_t)(r + 1) * P);
#pragma unroll
    for (int k = 0; k < 8; ++k) {
        float4 c4 = pf[k];
        if (MORE) pf[k] = CrowN[lane + (k << 6)];
        lse_push2(fmaf(c4.x, NS2F, u2), cm[k][0], cs[k][0]);
        lse_push2(fmaf(c4.y, NS2F, u2), cm[k][1], cs[k][1]);
        lse_push2(fmaf(c4.z, NS2F, u2), cm[k][2], cs[k][2]);
        lse_push2(fmaf(c4.w, NS2F, u2), cm[k][3], cs[k][3]);
    }
}

__global__ __launch_bounds__(512, 2) void iter_rowcol(
        const float* __restrict__ C, const float* __restrict__ vg,
        float* __restrict__ u, float2* __restrict__ part,
        float* __restrict__ errAcc, const unsigned* __restrict__ doneArr, int t) {
    if (doneArr[t]) return;
    __shared__ float sv[P];            // v * S2 (pre-scaled into exp2 domain)
    __shared__ float2 smrg[4][P];      // 64 KB merge buffer
    __shared__ float serr[8];
    const int tid = threadIdx.x, lane = tid & 63, wid = tid >> 6;
    const int b  = blockIdx.x >> 6;       // 64 blocks per batch
    const int q  = blockIdx.x & 63;       // row-block within batch
    const int r0 = q * ROWS_PER_BLK;
    const float* Cb = C + (size_t)b * P * P;
    const float eps_logmu = EPS * logf(1.0f / (float)P + 1e-8f);

    // stage scaled v: 512 threads x float4
    {
        float4 vv = ((const float4*)(vg + (size_t)b * P))[tid];
        vv.x *= S2F; vv.y *= S2F; vv.z *= S2F; vv.w *= S2F;
        ((float4*)sv)[tid] = vv;
    }

    // col chains: lane owns cols 4*(lane+64k)+c
    float cm[8][4], cs[8][4];
#pragma unroll
    for (int k = 0; k < 8; ++k)
#pragma unroll
        for (int c = 0; c < 4; ++c) { cm[k][c] = -INFINITY; cs[k][c] = 0.0f; }

    // prefetch first row of this wave
    float4 pf[8];
    {
        const float4* Crow = (const float4*)(Cb + (size_t)(r0 + (wid << 2)) * P);
#pragma unroll
        for (int k = 0; k < 8; ++k) pf[k] = Crow[lane + (k << 6)];
    }
    float werr = 0.0f;
    __syncthreads();                      // sv ready

    const int rb = r0 + (wid << 2);
    row_body<true >(Cb, sv, u, b, rb + 0, lane, pf, cm, cs, werr, eps_logmu);
    row_body<true >(Cb, sv, u, b, rb + 1, lane, pf, cm, cs, werr, eps_logmu);
    row_body<true >(Cb, sv, u, b, rb + 2, lane, pf, cm, cs, werr, eps_logmu);
    row_body<false>(Cb, sv, u, b, rb + 3, lane, pf, cm, cs, werr, eps_logmu);

    if (lane == 0) serr[wid] = werr;

    // ---- cross-wave merge tree: 8 -> 4 -> 2 -> 1 chains -------------------
    if (wid >= 4) {
#pragma unroll
        for (int k = 0; k < 8; ++k) {
            float2* dst = &smrg[wid - 4][(lane + (k << 6)) << 2];
            *(float4*)(dst)     = make_float4(cm[k][0], cs[k][0], cm[k][1], cs[k][1]);
            *(float4*)(dst + 2) = make_float4(cm[k][2], cs[k][2], cm[k][3], cs[k][3]);
        }
    }
    __syncthreads();
    if (tid == 0)
        atomicAdd(&errAcc[t], serr[0] + serr[1] + serr[2] + serr[3] +
                              serr[4] + serr[5] + serr[6] + serr[7]);
    if (wid < 4) {
#pragma unroll
        for (int k = 0; k < 8; ++k) {
            const float2* src = &smrg[wid][(lane + (k << 6)) << 2];
            float4 a  = *(const float4*)(src);
            float4 bq = *(const float4*)(src + 2);
            lse_merge2(a.x,  a.y,  cm[k][0], cs[k][0]);
            lse_merge2(a.z,  a.w,  cm[k][1], cs[k][1]);
            lse_merge2(bq.x, bq.y, cm[k][2], cs[k][2]);
            lse_merge2(bq.z, bq.w, cm[k][3], cs[k][3]);
        }
    }
    __syncthreads();
    if (wid == 2 || wid == 3) {
#pragma unroll
        for (int k = 0; k < 8; ++k) {
            float2* dst = &smrg[wid - 2][(lane + (k << 6)) << 2];
            *(float4*)(dst)     = make_float4(cm[k][0], cs[k][0], cm[k][1], cs[k][1]);
            *(float4*)(dst + 2) = make_float4(cm[k][2], cs[k][2], cm[k][3], cs[k][3]);
        }
    }
    __syncthreads();
    if (wid < 2) {
#pragma unroll
        for (int k = 0; k < 8; ++k) {
            const float2* src = &smrg[wid][(lane + (k << 6)) << 2];
            float4 a  = *(const float4*)(src);
            float4 bq = *(const float4*)(src + 2);
            lse_merge2(a.x,  a.y,  cm[k][0], cs[k][0]);
            lse_merge2(a.z,  a.w,  cm[k][1], cs[k][1]);
            lse_merge2(bq.x, bq.y, cm[k][2], cs[k][2]);
            lse_merge2(bq.z, bq.w, cm[k][3], cs[k][3]);
        }
    }
    __syncthreads();
    if (wid == 1) {
#pragma unroll
        for (int k = 0; k < 8; ++k) {
            float2* dst = &smrg[0][(lane + (k << 6)) << 2];
            *(float4*)(dst)     = make_float4(cm[k][0], cs[k][0], cm[k][1], cs[k][1]);
            *(float4*)(dst + 2) = make_float4(cm[k][2], cs[k][2], cm[k][3], cs[k][3]);
        }
    }
    __syncthreads();
    if (wid == 0) {
        float2* pbase = part + ((size_t)q * B + b) * P;
#pragma unroll
        for (int k = 0; k < 8; ++k) {
            const float2* src = &smrg[0][(lane + (k << 6)) << 2];
            float4 a  = *(const float4*)(src);
            float4 bq = *(const float4*)(src + 2);
            lse_merge2(a.x,  a.y,  cm[k][0], cs[k][0]);
            lse_merge2(a.z,  a.w,  cm[k][1], cs[k][1]);
            lse_merge2(bq.x, bq.y, cm[k][2], cs[k][2]);
            lse_merge2(bq.z, bq.w, cm[k][3], cs[k][3]);
            float2* dst = &pbase[(lane + (k << 6)) << 2];
            *(float4*)(dst)     = make_float4(cm[k][0], cs[k][0], cm[k][1], cs[k][1]);
            *(float4*)(dst + 2) = make_float4(cm[k][2], cs[k][2], cm[k][3], cs[k][3]);
        }
    }
}

// ---- iteration kernel B: merge 64 planes -> v; latch done flag ------------
// 256 blocks x 256 threads; a block owns 64 columns; 4 threads per column,
// each merging 16 planes (2 independent chains), then LDS tree-reduce.
// Chain state is exp2-domain (m = max z2, s = sum 2^(z2-m)).
__global__ __launch_bounds__(256) void iter_merge(
        const float2* __restrict__ part, float* __restrict__ vg,
        const float* __restrict__ errAcc, unsigned* __restrict__ doneArr, int t) {
    __shared__ float2 sred[3][64];
    const int tid = threadIdx.x;
    if (blockIdx.x == 0 && tid == 0) {
        // errAcc[t]==0 when frozen, so the latch self-propagates.
        doneArr[t + 1] = doneArr[t] | (errAcc[t] < THRESH * (float)B ? 1u : 0u);
    }
    if (doneArr[t]) return;
    const int cl = tid & 63;              // column within block
    const int g  = tid >> 6;              // plane group 0..3
    const size_t idx = (size_t)blockIdx.x * 64 + cl;   // global column
    float m[2] = {-INFINITY, -INFINITY}, s[2] = {0.0f, 0.0f};
#pragma unroll
    for (int k = 0; k < 8; ++k) {
#pragma unroll
        for (int c = 0; c < 2; ++c) {
            int qq = g * 16 + k * 2 + c;
            float2 pk = part[(size_t)qq * (B * P) + idx];
            lse_merge2(pk.x, pk.y, m[c], s[c]);
        }
    }
    lse_merge2(m[1], s[1], m[0], s[0]);
    if (g) sred[g - 1][cl] = make_float2(m[0], s[0]);
    __syncthreads();
    if (g == 0) {
#pragma unroll
        for (int gg = 0; gg < 3; ++gg) {
            float2 o = sred[gg][cl];
            lse_merge2(o.x, o.y, m[0], s[0]);
        }
        const float eps_logmu = EPS * logf(1.0f / (float)P + 1e-8f);  // log_nu == log_mu
        vg[idx] = eps_logmu - EPSLN2 * (m[0] + LOG2F(s[0]));
    }
}

// ---- final: pi = exp((u+v-C)/eps), cost[b] = sum pi*C ---------------------
// 1024 blocks * 4 waves * 4 rows = 16384 rows = B*P.
__global__ __launch_bounds__(256) void final_pi_cost(
        const float* __restrict__ C, const float* __restrict__ u,
        const float* __restrict__ vg, float* __restrict__ pi,
        float* __restrict__ cost) {
    __shared__ float sc[B];
    const int tid = threadIdx.x, lane = tid & 63, wid = tid >> 6;
    if (tid < B) sc[tid] = 0.0f;
    __syncthreads();
    const int gw = blockIdx.x * 4 + wid;      // 0..4095
    const int rbase = gw * 4;
    if (rbase >= B * P) return;               // defensive
    const int b = rbase >> 11;
    const float4* vrow = (const float4*)(vg + b * P);
    float acc = 0.0f;
    for (int k = 0; k < 4; ++k) {
        const int r = rbase + k;
        const float ur = u[r];
        const float4* Crow = (const float4*)(C + (size_t)r * P);
        float4* prow = (float4*)(pi + (size_t)r * P);
        for (int it = lane; it < P / 4; it += 64) {
            float4 c4 = Crow[it];
            float4 v4 = vrow[it];
            float4 p4;
            p4.x = __expf((ur + v4.x - c4.x) * INVEPS);
            p4.y = __expf((ur + v4.y - c4.y) * INVEPS);
            p4.z = __expf((ur + v4.z - c4.z) * INVEPS);
            p4.w = __expf((ur + v4.w - c4.w) * INVEPS);
            prow[it] = p4;
            acc += p4.x * c4.x + p4.y * c4.y + p4.z * c4.z + p4.w * c4.w;
        }
    }
#pragma unroll
    for (int off = 32; off; off >>= 1) acc += __shfl_xor(acc, off, 64);
    if (lane == 0) atomicAdd(&sc[b], acc);
    __syncthreads();
    if (tid < B && sc[tid] != 0.0f) atomicAdd(&cost[tid], sc[tid]);
}

extern "C" void kernel_launch(void* const* d_in, const int* in_sizes, int n_in,
                              void* d_out, int out_size, void* d_ws, size_t ws_size,
                              hipStream_t stream) {
    const float* x = (const float*)d_in[0];
    const float* y = (const float*)d_in[1];
    float* out  = (float*)d_out;
    float* cost = out;                              // [8]
    float* pi   = out + 8;                          // [8*2048*2048]
    float* C    = out + 8 + (size_t)B * P * P;      // [8*2048*2048]

    // Column partials live in the pi output region (scratch until final pass):
    // PLANES * B*P float2 = 8 MB << 134 MB.
    float2* part = (float2*)pi;

    float* ws      = (float*)d_ws;
    float* u       = ws;                            // B*P
    float* v       = ws + B * P;                    // B*P
    float* errAcc  = ws + 2 * B * P;                // MAXIT
    unsigned* doneArr = (unsigned*)(ws + 2 * B * P + 128);  // MAXIT+1

    hipLaunchKernelGGL(build_C, dim3(8 * 32 * 32), dim3(256), 0, stream, x, y, C);
    hipLaunchKernelGGL(init_ws, dim3(64), dim3(256), 0, stream,
                       u, v, errAcc, doneArr, cost);

    for (int t = 0; t < MAXIT; ++t) {
        hipLaunchKernelGGL(iter_rowcol, dim3(NBLK_A), dim3(512), 0, stream,
                           (const float*)C, (const float*)v, u, part,
                           errAcc, (const unsigned*)doneArr, t);
        hipLaunchKernelGGL(iter_merge, dim3(B * P / 64), dim3(256), 0, stream,
                           (const float2*)part, v, (const float*)errAcc,
                           doneArr, t);
    }

    hipLaunchKernelGGL(final_pi_cost, dim3(1024), dim3(256), 0, stream,
                       (const float*)C, (const float*)u, (const float*)v,
                       pi, cost);
}